// Round 4
// baseline (753.235 us; speedup 1.0000x reference)
//
#include <hip/hip_runtime.h>

#define NN 100000
#define NE 6400000
#define BSZ 64                   // nodes per bucket
#define NBKT 1563                // ceil(NN/BSZ)
#define NB 512                   // sort blocks
#define CHUNK 12500              // NE/NB exactly
#define TOTBINS (NBKT * NB)      // 800256
#define NCH 782                  // ceil(TOTBINS/1024)
#define PADH 9                   // padded LDS row stride for 8-float half rows

// ============================ fast path ============================

// X[b*NBKT + k] = count of edges in chunk b destined to bucket k
__global__ __launch_bounds__(512) void histA(const int* __restrict__ col, int* __restrict__ X) {
    __shared__ int h[NBKT];
    for (int i = threadIdx.x; i < NBKT; i += 512) h[i] = 0;
    __syncthreads();
    const int* c = col + blockIdx.x * CHUNK;
    for (int i = threadIdx.x; i < CHUNK; i += 512)
        atomicAdd(&h[c[i] >> 6], 1);
    __syncthreads();
    int* o = X + blockIdx.x * NBKT;
    for (int i = threadIdx.x; i < NBKT; i += 512) o[i] = h[i];
}

// in-place exclusive scan of X over logical order idx = k*NB + b, chunked by 1024
__global__ __launch_bounds__(256) void scan1(int* __restrict__ X, int* __restrict__ ctot) {
    __shared__ int buf[1024];
    __shared__ int ts[256];
    int base = blockIdx.x << 10;
    for (int j = threadIdx.x; j < 1024; j += 256) {
        int idx = base + j;
        int v = 0;
        if (idx < TOTBINS) {
            int k = idx >> 9, b = idx & 511;
            v = X[b * NBKT + k];
        }
        buf[j] = v;
    }
    __syncthreads();
    int j0 = threadIdx.x * 4;
    int a0 = buf[j0], a1 = buf[j0 + 1], a2 = buf[j0 + 2], a3 = buf[j0 + 3];
    int s = a0 + a1 + a2 + a3;
    ts[threadIdx.x] = s;
    __syncthreads();
    for (int off = 1; off < 256; off <<= 1) {
        int u = (threadIdx.x >= off) ? ts[threadIdx.x - off] : 0;
        __syncthreads();
        ts[threadIdx.x] += u;
        __syncthreads();
    }
    int eb0 = ts[threadIdx.x] - s;
    int ev[4] = {eb0, eb0 + a0, eb0 + a0 + a1, eb0 + a0 + a1 + a2};
#pragma unroll
    for (int t = 0; t < 4; ++t) {
        int idx = base + j0 + t;
        if (idx < TOTBINS) {
            int k = idx >> 9, b = idx & 511;
            X[b * NBKT + k] = ev[t];
        }
    }
    if (threadIdx.x == 255) ctot[blockIdx.x] = ts[255];
}

__global__ void scan2(const int* __restrict__ ctot, int* __restrict__ cbase) {
    __shared__ int ts[1024];
    int t = threadIdx.x;
    int orig = (t < NCH) ? ctot[t] : 0;
    ts[t] = orig;
    __syncthreads();
    for (int off = 1; off < 1024; off <<= 1) {
        int u = (t >= off) ? ts[t - off] : 0;
        __syncthreads();
        ts[t] += u;
        __syncthreads();
    }
    if (t < NCH) cbase[t] = ts[t] - orig;
}

__global__ __launch_bounds__(256) void scan3(int* __restrict__ X, const int* __restrict__ cbase) {
    int m = blockIdx.x * 256 + threadIdx.x;
    if (m >= TOTBINS) return;
    int b = m / NBKT;
    int k = m - b * NBKT;
    int idx = (k << 9) | b;
    X[m] += cbase[idx >> 10];
}

// scatter edges into bucket-sorted eb; pack (slot<<17 | row)
__global__ __launch_bounds__(512) void passB(const int* __restrict__ row, const int* __restrict__ col,
                                             const int* __restrict__ X, int* __restrict__ eb) {
    __shared__ int cur[NBKT];
    const int* st = X + blockIdx.x * NBKT;
    for (int i = threadIdx.x; i < NBKT; i += 512) cur[i] = st[i];
    __syncthreads();
    const int* r = row + blockIdx.x * CHUNK;
    const int* c = col + blockIdx.x * CHUNK;
    for (int i = threadIdx.x; i < CHUNK; i += 512) {
        int cc = c[i];
        int pos = atomicAdd(&cur[cc >> 6], 1);
        eb[pos] = r[i] | ((cc & 63) << 17);
    }
}

// degree -> dinv, fused with g1a/g1b[i][f] = dinv[i] * (x[i] @ W1)[f] (split halves)
__global__ __launch_bounds__(256) void passC(const int* __restrict__ eb, const int* __restrict__ X,
                                             const float* __restrict__ x, const float* __restrict__ W1,
                                             float* __restrict__ dinv, float* __restrict__ g1a,
                                             float* __restrict__ g1b) {
    __shared__ int cnt[BSZ];
    __shared__ float sW[144];
    int k = blockIdx.x;
    if (threadIdx.x < BSZ) cnt[threadIdx.x] = 0;
    for (int i = threadIdx.x; i < 144; i += 256) sW[i] = W1[i];
    int s = X[k];
    int e = (k + 1 < NBKT) ? X[k + 1] : NE;
    __syncthreads();
    {
        int i = s + (int)threadIdx.x;
        int nIter = (e - s + 255) >> 8;
        int p = (i < e) ? __builtin_nontemporal_load(&eb[i]) : -1;
        for (int t = 0; t < nIter; ++t) {
            int inext = i + 256;
            int pnext = (inext < e) ? __builtin_nontemporal_load(&eb[inext]) : -1;
            if (p >= 0) atomicAdd(&cnt[p >> 17], 1);
            p = pnext; i = inext;
        }
    }
    __syncthreads();
    int node0 = k * BSZ;
    if (threadIdx.x < BSZ) {
        int node = node0 + threadIdx.x;
        if (node < NN) dinv[node] = rsqrtf((float)cnt[threadIdx.x] + 1.0f);
    }
    int ln = threadIdx.x >> 2;            // 0..63
    int node = node0 + ln;
    if (node < NN) {
        float di = rsqrtf((float)cnt[ln] + 1.0f);
        int fq = (threadIdx.x & 3) << 2;  // 0,4,8,12
        float xr[9];
#pragma unroll
        for (int q = 0; q < 9; ++q) xr[q] = x[node * 9 + q];
#pragma unroll
        for (int j = 0; j < 4; ++j) {
            int f = fq + j;
            float a = 0.f;
#pragma unroll
            for (int q = 0; q < 9; ++q) a = fmaf(xr[q], sW[q * 16 + f], a);
            a *= di;
            if (f < 8) g1a[(node << 3) + f] = a;
            else       g1b[(node << 3) + (f - 8)] = a;
        }
    }
}

// one half of layer-1 aggregate + relu + partial layer-2 dot.
// HALF=0: h2part_out[c] = sum_{f<8} relu(...)W2[f]
// HALF=1: gg[c] = dinv[c] * (h2part_in[c] + sum_{f>=8} relu(...)W2[f])
template <int HALF>
__global__ __launch_bounds__(256) void passE(const int* __restrict__ eb, const int* __restrict__ X,
                                             const float* __restrict__ g1h, const float* __restrict__ dinv,
                                             const float* __restrict__ b1, const float* __restrict__ W2,
                                             const float* __restrict__ h2part_in,
                                             float* __restrict__ outv) {
    __shared__ float acc[BSZ * PADH];     // 2304 B
    __shared__ float sb[8], sw[8];
    int k = blockIdx.x;
    for (int i = threadIdx.x; i < BSZ * PADH; i += 256) acc[i] = 0.f;
    if (threadIdx.x < 8) {
        sb[threadIdx.x] = b1[HALF * 8 + threadIdx.x];
        sw[threadIdx.x] = W2[HALF * 8 + threadIdx.x];
    }
    int s = X[k];
    int e = (k + 1 < NBKT) ? X[k + 1] : NE;
    __syncthreads();
    int nIter = (e - s + 255) >> 8;
    int i = s + (int)threadIdx.x;
    int p = (i < e) ? __builtin_nontemporal_load(&eb[i]) : -1;
    for (int t = 0; t < nIter; ++t) {
        int inext = i + 256;
        int pnext = (inext < e) ? __builtin_nontemporal_load(&eb[inext]) : -1;
        if (p >= 0) {
            int r = p & 0x1FFFF;
            int slot = p >> 17;
            const float4* gp = (const float4*)(g1h + (r << 3));
            float4 v0 = gp[0], v1 = gp[1];
            float* a = acc + slot * PADH;
            atomicAdd(a + 0, v0.x); atomicAdd(a + 1, v0.y);
            atomicAdd(a + 2, v0.z); atomicAdd(a + 3, v0.w);
            atomicAdd(a + 4, v1.x); atomicAdd(a + 5, v1.y);
            atomicAdd(a + 6, v1.z); atomicAdd(a + 7, v1.w);
        }
        p = pnext; i = inext;
    }
    __syncthreads();
    if (threadIdx.x < BSZ) {
        int node = k * BSZ + threadIdx.x;
        if (node < NN) {
            float di = dinv[node];
            float h2 = 0.f;
#pragma unroll
            for (int ff = 0; ff < 8; ++ff) {
                float v = di * (acc[threadIdx.x * PADH + ff] + g1h[(node << 3) + ff]) + sb[ff];
                h2 = fmaf(fmaxf(v, 0.f), sw[ff], h2);
            }
            if (HALF == 0) outv[node] = h2;
            else           outv[node] = di * (h2part_in[node] + h2);
        }
    }
}

// layer2 aggregate + finalize
__global__ __launch_bounds__(256) void passF(const int* __restrict__ eb, const int* __restrict__ X,
                                             const float* __restrict__ gg, const float* __restrict__ dinv,
                                             const float* __restrict__ b2, float* __restrict__ out) {
    __shared__ float acc[BSZ];
    int k = blockIdx.x;
    if (threadIdx.x < BSZ) acc[threadIdx.x] = 0.f;
    int s = X[k];
    int e = (k + 1 < NBKT) ? X[k + 1] : NE;
    __syncthreads();
    int nIter = (e - s + 255) >> 8;
    int i = s + (int)threadIdx.x;
    int p = (i < e) ? __builtin_nontemporal_load(&eb[i]) : -1;
    for (int t = 0; t < nIter; ++t) {
        int inext = i + 256;
        int pnext = (inext < e) ? __builtin_nontemporal_load(&eb[inext]) : -1;
        if (p >= 0) atomicAdd(&acc[p >> 17], gg[p & 0x1FFFF]);
        p = pnext; i = inext;
    }
    __syncthreads();
    if (threadIdx.x < BSZ) {
        int node = k * BSZ + threadIdx.x;
        if (node < NN)
            out[node] = fmaxf(dinv[node] * (acc[threadIdx.x] + gg[node]) + b2[0], 0.f);
    }
}

// ============================ fallback path (global atomics) ============================

__global__ void fb_deg(const int* __restrict__ col, float* __restrict__ deg, int E) {
    int stride = gridDim.x * blockDim.x;
    for (int i = blockIdx.x * blockDim.x + threadIdx.x; i < E; i += stride)
        atomicAdd(&deg[col[i]], 1.0f);
}
__global__ void fb_dinv(float* __restrict__ d, int N) {
    int i = blockIdx.x * blockDim.x + threadIdx.x;
    if (i < N) d[i] = rsqrtf(d[i] + 1.0f);
}
__global__ void fb_h1p(const float* __restrict__ x, const float* __restrict__ W1, float* __restrict__ h1p, int N) {
    __shared__ float sW[144];
    if (threadIdx.x < 144) sW[threadIdx.x] = W1[threadIdx.x];
    __syncthreads();
    int i = blockIdx.x * blockDim.x + threadIdx.x;
    if (i >= N) return;
    float xi[9];
#pragma unroll
    for (int q = 0; q < 9; ++q) xi[q] = x[i * 9 + q];
#pragma unroll
    for (int ff = 0; ff < 16; ++ff) {
        float a = 0.f;
#pragma unroll
        for (int q = 0; q < 9; ++q) a = fmaf(xi[q], sW[q * 16 + ff], a);
        h1p[i * 16 + ff] = a;
    }
}
__global__ void fb_sc1(const int* __restrict__ row, const int* __restrict__ col, const float* __restrict__ dinv,
                       const float* __restrict__ h1p, float* __restrict__ agg1, long total) {
    long stride = (long)gridDim.x * blockDim.x;
    for (long t = (long)blockIdx.x * blockDim.x + threadIdx.x; t < total; t += stride) {
        int e = (int)(t >> 4), ff = (int)(t & 15);
        int r = row[e], c = col[e];
        atomicAdd(&agg1[c * 16 + ff], h1p[r * 16 + ff] * dinv[r] * dinv[c]);
    }
}
__global__ void fb_fin1(const float* __restrict__ agg1, const float* __restrict__ h1p, const float* __restrict__ dinv,
                        const float* __restrict__ b1, const float* __restrict__ W2, float* __restrict__ h2p, int N) {
    __shared__ float sW2[16], sb1[16];
    if (threadIdx.x < 16) { sW2[threadIdx.x] = W2[threadIdx.x]; sb1[threadIdx.x] = b1[threadIdx.x]; }
    __syncthreads();
    int i = blockIdx.x * blockDim.x + threadIdx.x;
    if (i >= N) return;
    float di = dinv[i], self = di * di, a = 0.f;
#pragma unroll
    for (int ff = 0; ff < 16; ++ff) {
        float v = agg1[i * 16 + ff] + h1p[i * 16 + ff] * self + sb1[ff];
        a = fmaf(fmaxf(v, 0.f), sW2[ff], a);
    }
    h2p[i] = a;
}
__global__ void fb_sc2(const int* __restrict__ row, const int* __restrict__ col, const float* __restrict__ dinv,
                       const float* __restrict__ h2p, float* __restrict__ out, int E) {
    int stride = gridDim.x * blockDim.x;
    for (int e = blockIdx.x * blockDim.x + threadIdx.x; e < E; e += stride) {
        int r = row[e], c = col[e];
        atomicAdd(&out[c], h2p[r] * dinv[r] * dinv[c]);
    }
}
__global__ void fb_fin2(float* __restrict__ out, const float* __restrict__ h2p, const float* __restrict__ dinv,
                        const float* __restrict__ b2, int N) {
    int i = blockIdx.x * blockDim.x + threadIdx.x;
    if (i < N) {
        float di = dinv[i];
        out[i] = fmaxf(out[i] + h2p[i] * di * di + b2[0], 0.f);
    }
}

// ============================ launcher ============================

extern "C" void kernel_launch(void* const* d_in, const int* in_sizes, int n_in,
                              void* d_out, int out_size, void* d_ws, size_t ws_size,
                              hipStream_t stream) {
    const float* x  = (const float*)d_in[0];
    const int*   ei = (const int*)d_in[1];
    const float* W1 = (const float*)d_in[2];
    const float* b1 = (const float*)d_in[3];
    const float* W2 = (const float*)d_in[4];
    const float* b2 = (const float*)d_in[5];
    float* out = (float*)d_out;
    const int* row = ei;
    const int* col = ei + NE;
    char* ws = (char*)d_ws;

    constexpr size_t OFF_EB = 0;                       // 25,600,000 B
    constexpr size_t OFF_X  = 25600000;                // 3,201,024 B
    constexpr size_t OFF_CT = OFF_X + 3201024;         // 4096 B
    constexpr size_t OFF_CB = OFF_CT + 4096;           // 4096 B
    constexpr size_t OFF_DI = OFF_CB + 4096;           // 400,128 B
    constexpr size_t OFF_GA = OFF_DI + 400128;         // 3,200,000 B (half features 0-7)
    constexpr size_t OFF_GB = OFF_GA + 3200000;        // 3,200,000 B (half features 8-15)
    constexpr size_t OFF_H2 = OFF_GB + 3200000;        // 400,000 B (partial h2)
    constexpr size_t OFF_GG = OFF_H2 + 400000;         // 400,000 B
    constexpr size_t WS_NEED = OFF_GG + 400000;        // ~36.4 MB

    if (ws_size >= WS_NEED) {
        int*   eb    = (int*)(ws + OFF_EB);
        int*   X     = (int*)(ws + OFF_X);
        int*   ctot  = (int*)(ws + OFF_CT);
        int*   cbase = (int*)(ws + OFF_CB);
        float* dinv  = (float*)(ws + OFF_DI);
        float* g1a   = (float*)(ws + OFF_GA);
        float* g1b   = (float*)(ws + OFF_GB);
        float* h2a   = (float*)(ws + OFF_H2);
        float* gg    = (float*)(ws + OFF_GG);

        histA<<<NB, 512, 0, stream>>>(col, X);
        scan1<<<NCH, 256, 0, stream>>>(X, ctot);
        scan2<<<1, 1024, 0, stream>>>(ctot, cbase);
        scan3<<<(TOTBINS + 255) / 256, 256, 0, stream>>>(X, cbase);
        passB<<<NB, 512, 0, stream>>>(row, col, X, eb);
        passC<<<NBKT, 256, 0, stream>>>(eb, X, x, W1, dinv, g1a, g1b);
        passE<0><<<NBKT, 256, 0, stream>>>(eb, X, g1a, dinv, b1, W2, nullptr, h2a);
        passE<1><<<NBKT, 256, 0, stream>>>(eb, X, g1b, dinv, b1, W2, h2a, gg);
        passF<<<NBKT, 256, 0, stream>>>(eb, X, gg, dinv, b2, out);
    } else {
        // fallback: global-atomic version (needs ~13.8 MB)
        float* dinv = (float*)(ws);
        float* h1p  = (float*)(ws + 524288);
        float* agg1 = (float*)(ws + 6924288);
        float* h2p  = (float*)(ws + 13324288);
        hipMemsetAsync(dinv, 0, NN * sizeof(float), stream);
        hipMemsetAsync(agg1, 0, NN * 16 * sizeof(float), stream);
        hipMemsetAsync(out, 0, NN * sizeof(float), stream);
        const int B = 256;
        int gridN = (NN + B - 1) / B;
        fb_deg<<<4096, B, 0, stream>>>(col, dinv, NE);
        fb_dinv<<<gridN, B, 0, stream>>>(dinv, NN);
        fb_h1p<<<gridN, B, 0, stream>>>(x, W1, h1p, NN);
        fb_sc1<<<8192, B, 0, stream>>>(row, col, dinv, h1p, agg1, (long)NE * 16);
        fb_fin1<<<gridN, B, 0, stream>>>(agg1, h1p, dinv, b1, W2, h2p, NN);
        fb_sc2<<<4096, B, 0, stream>>>(row, col, dinv, h2p, out, NE);
        fb_fin2<<<gridN, B, 0, stream>>>(out, h2p, dinv, b2, NN);
    }
}

// Round 5
// 384.899 us; speedup vs baseline: 1.9570x; 1.9570x over previous
//
#include <hip/hip_runtime.h>

#define NN 100000
#define NE 6400000
#define BSZ 16                    // nodes per bucket
#define NBKT 6250                 // NN/BSZ exactly
#define NB 256                    // sort chunks
#define CHUNK 25000               // NE/NB exactly
#define TOTBINS (NBKT * NB)       // 1,600,000
#define SC1 2048                  // elems per scan1 block
#define NCH ((TOTBINS + SC1 - 1) / SC1)   // 782

// ============================ fast path ============================

// X[b*NBKT + k] = count of edges in chunk b destined to bucket k
__global__ __launch_bounds__(512) void histA(const int* __restrict__ col, int* __restrict__ X) {
    __shared__ int h[NBKT];
    for (int i = threadIdx.x; i < NBKT; i += 512) h[i] = 0;
    __syncthreads();
    const int* c = col + blockIdx.x * CHUNK;
    for (int i = threadIdx.x; i < CHUNK; i += 512)
        atomicAdd(&h[c[i] >> 4], 1);
    __syncthreads();
    int* o = X + blockIdx.x * NBKT;
    for (int i = threadIdx.x; i < NBKT; i += 512) o[i] = h[i];
}

// in-place exclusive scan over logical order idx = k*NB + b (storage X[b*NBKT+k])
__global__ __launch_bounds__(512) void scan1(int* __restrict__ X, int* __restrict__ ctot) {
    __shared__ int buf[SC1];
    __shared__ int ts[512];
    int base = blockIdx.x * SC1;
    for (int j = threadIdx.x; j < SC1; j += 512) {
        int idx = base + j; int v = 0;
        if (idx < TOTBINS) { int k = idx >> 8, b = idx & 255; v = X[b * NBKT + k]; }
        buf[j] = v;
    }
    __syncthreads();
    int j0 = threadIdx.x * 4;
    int a0 = buf[j0], a1 = buf[j0 + 1], a2 = buf[j0 + 2], a3 = buf[j0 + 3];
    int s = a0 + a1 + a2 + a3;
    ts[threadIdx.x] = s;
    __syncthreads();
    for (int off = 1; off < 512; off <<= 1) {
        int u = (threadIdx.x >= off) ? ts[threadIdx.x - off] : 0;
        __syncthreads();
        ts[threadIdx.x] += u;
        __syncthreads();
    }
    int e0 = ts[threadIdx.x] - s;
    int ev[4] = {e0, e0 + a0, e0 + a0 + a1, e0 + a0 + a1 + a2};
#pragma unroll
    for (int t = 0; t < 4; ++t) {
        int idx = base + j0 + t;
        if (idx < TOTBINS) { int k = idx >> 8, b = idx & 255; X[b * NBKT + k] = ev[t]; }
    }
    if (threadIdx.x == 511) ctot[blockIdx.x] = ts[511];
}

__global__ void scan2(const int* __restrict__ ctot, int* __restrict__ cbase) {
    __shared__ int ts[1024];
    int t = threadIdx.x;
    int orig = (t < NCH) ? ctot[t] : 0;
    ts[t] = orig;
    __syncthreads();
    for (int off = 1; off < 1024; off <<= 1) {
        int u = (t >= off) ? ts[t - off] : 0;
        __syncthreads();
        ts[t] += u;
        __syncthreads();
    }
    if (t < NCH) cbase[t] = ts[t] - orig;
}

__global__ __launch_bounds__(256) void scan3(int* __restrict__ X, const int* __restrict__ cbase) {
    int m = blockIdx.x * 256 + threadIdx.x;
    if (m >= TOTBINS) return;
    int b = m / NBKT;
    int k = m - b * NBKT;
    int idx = (k << 8) | b;
    X[m] += cbase[idx >> 11];     // SC1 = 2048
}

// scatter edges into bucket-sorted eb; pack (slot<<17 | row), slot = 4 bits
__global__ __launch_bounds__(512) void passB(const int* __restrict__ row, const int* __restrict__ col,
                                             const int* __restrict__ X, int* __restrict__ eb) {
    __shared__ int cur[NBKT];
    const int* st = X + blockIdx.x * NBKT;
    for (int i = threadIdx.x; i < NBKT; i += 512) cur[i] = st[i];
    __syncthreads();
    const int* r = row + blockIdx.x * CHUNK;
    const int* c = col + blockIdx.x * CHUNK;
    for (int i = threadIdx.x; i < CHUNK; i += 512) {
        int cc = c[i];
        int pos = atomicAdd(&cur[cc >> 4], 1);
        eb[pos] = r[i] | ((cc & 15) << 17);
    }
}

// degree (register cndmask count) -> dinv, fused with g1a/g1b = dinv * (x@W1) halves
__global__ __launch_bounds__(256) void passC(const int* __restrict__ eb, const int* __restrict__ X,
                                             const float* __restrict__ x, const float* __restrict__ W1,
                                             float* __restrict__ dinv, float* __restrict__ g1a,
                                             float* __restrict__ g1b) {
    __shared__ float sW[144];
    __shared__ int cdeg[4][16];
    for (int i = threadIdx.x; i < 144; i += 256) sW[i] = W1[i];
    int w = threadIdx.x >> 6, lane = threadIdx.x & 63;
    int k = blockIdx.x * 4 + w;
    if (k < NBKT) {
        int s = X[k], e = (k + 1 < NBKT) ? X[k + 1] : NE;
        int m4 = (lane & 3) * 4;
        int deg4[4] = {0, 0, 0, 0};
        for (int i = s + (lane >> 2); i < e; i += 16) {
            int p = eb[i];
            int slot = (p >> 17) & 15;
#pragma unroll
            for (int t = 0; t < 4; ++t) deg4[t] += (slot == m4 + t) ? 1 : 0;
        }
#pragma unroll
        for (int d = 4; d < 64; d <<= 1)
#pragma unroll
            for (int t = 0; t < 4; ++t) deg4[t] += __shfl_xor(deg4[t], d);
        if (lane < 4)
#pragma unroll
            for (int t = 0; t < 4; ++t) cdeg[w][lane * 4 + t] = deg4[t];
    }
    __syncthreads();
    if (k < NBKT) {
        int node0 = k * BSZ;
        if (lane < 16) dinv[node0 + lane] = rsqrtf((float)cdeg[w][lane] + 1.f);
        int nd = lane >> 2, fq = lane & 3;
        int node = node0 + nd;
        float di = rsqrtf((float)cdeg[w][nd] + 1.f);
        float xr[9];
#pragma unroll
        for (int q = 0; q < 9; ++q) xr[q] = x[node * 9 + q];
        float4 o;
        float* op = &o.x;
#pragma unroll
        for (int j = 0; j < 4; ++j) {
            int f = fq * 4 + j;
            float a = 0.f;
#pragma unroll
            for (int q = 0; q < 9; ++q) a = fmaf(xr[q], sW[q * 16 + f], a);
            op[j] = a * di;
        }
        if (fq < 2) *(float4*)(g1a + node * 8 + fq * 4) = o;
        else        *(float4*)(g1b + node * 8 + (fq - 2) * 4) = o;
    }
}

// half of layer-1: register accumulate + relu + partial layer-2 dot.
// HALF=0: outv[n] = partial h2 (features 0-7). HALF=1: outv[n] = gg[n] = dinv*(h2a+partial).
template <int HALF>
__global__ __launch_bounds__(256) void passE(const int* __restrict__ eb, const int* __restrict__ X,
                                             const float* __restrict__ g1h, const float* __restrict__ dinv,
                                             const float* __restrict__ b1, const float* __restrict__ W2,
                                             const float* __restrict__ h2a, float* __restrict__ outv) {
    __shared__ float sb[8], sw[8];
    if (threadIdx.x < 8) {
        sb[threadIdx.x] = b1[HALF * 8 + threadIdx.x];
        sw[threadIdx.x] = W2[HALF * 8 + threadIdx.x];
    }
    __syncthreads();
    int w = threadIdx.x >> 6, lane = threadIdx.x & 63;
    int k = blockIdx.x * 4 + w;
    if (k >= NBKT) return;
    int s = X[k], e = (k + 1 < NBKT) ? X[k + 1] : NE;
    int j = lane & 3, ego = lane >> 2;
    float2 acc[16];
#pragma unroll
    for (int t = 0; t < 16; ++t) { acc[t].x = 0.f; acc[t].y = 0.f; }
    int nIter = (e - s + 15) >> 4;
    int i = s + ego;
    int p = (i < e) ? eb[i] : -1;
    for (int it = 0; it < nIter; ++it) {
        int inext = i + 16;
        int pnext = (inext < e) ? eb[inext] : -1;
        if (p >= 0) {
            int r = p & 0x1FFFF, slot = (p >> 17) & 15;
            float2 g = *(const float2*)(g1h + r * 8 + j * 2);
#pragma unroll
            for (int t = 0; t < 16; ++t) {
                float m = (slot == t) ? 1.f : 0.f;
                acc[t].x = fmaf(m, g.x, acc[t].x);
                acc[t].y = fmaf(m, g.y, acc[t].y);
            }
        }
        p = pnext; i = inext;
    }
#pragma unroll
    for (int d = 4; d < 64; d <<= 1)
#pragma unroll
        for (int t = 0; t < 16; ++t) {
            acc[t].x += __shfl_xor(acc[t].x, d);
            acc[t].y += __shfl_xor(acc[t].y, d);
        }
    // epilogue: lanes within each 4-group hold f-pair (2j, 2j+1)
    float w0 = sw[2 * j], w1 = sw[2 * j + 1], bb0 = sb[2 * j], bb1 = sb[2 * j + 1];
#pragma unroll
    for (int t = 0; t < 16; ++t) {
        int node = k * BSZ + t;
        float di = dinv[node];
        float2 gs = *(const float2*)(g1h + node * 8 + j * 2);
        float v0 = fmaxf(di * (acc[t].x + gs.x) + bb0, 0.f);
        float v1 = fmaxf(di * (acc[t].y + gs.y) + bb1, 0.f);
        float part = fmaf(v1, w1, v0 * w0);
        part += __shfl_xor(part, 1);
        part += __shfl_xor(part, 2);
        if (lane == 0) {
            if (HALF == 0) outv[node] = part;
            else           outv[node] = di * (h2a[node] + part);
        }
    }
}

// layer-2 aggregate (register) + finalize
__global__ __launch_bounds__(256) void passF(const int* __restrict__ eb, const int* __restrict__ X,
                                             const float* __restrict__ gg, const float* __restrict__ dinv,
                                             const float* __restrict__ b2, float* __restrict__ out) {
    int w = threadIdx.x >> 6, lane = threadIdx.x & 63;
    int k = blockIdx.x * 4 + w;
    if (k >= NBKT) return;
    int s = X[k], e = (k + 1 < NBKT) ? X[k + 1] : NE;
    int m4 = (lane & 3) * 4;
    float acc[4] = {0.f, 0.f, 0.f, 0.f};
    int nIter = (e - s + 15) >> 4;
    int i = s + (lane >> 2);
    int p = (i < e) ? eb[i] : -1;
    for (int it = 0; it < nIter; ++it) {
        int inext = i + 16;
        int pnext = (inext < e) ? eb[inext] : -1;
        if (p >= 0) {
            int r = p & 0x1FFFF, slot = (p >> 17) & 15;
            float v = gg[r];
#pragma unroll
            for (int t = 0; t < 4; ++t) {
                float m = (slot == m4 + t) ? 1.f : 0.f;
                acc[t] = fmaf(m, v, acc[t]);
            }
        }
        p = pnext; i = inext;
    }
#pragma unroll
    for (int d = 4; d < 64; d <<= 1)
#pragma unroll
        for (int t = 0; t < 4; ++t) acc[t] += __shfl_xor(acc[t], d);
    if (lane < 4) {
        float b = b2[0];
#pragma unroll
        for (int t = 0; t < 4; ++t) {
            int node = k * BSZ + lane * 4 + t;
            out[node] = fmaxf(dinv[node] * (acc[t] + gg[node]) + b, 0.f);
        }
    }
}

// ============================ fallback path (global atomics) ============================

__global__ void fb_deg(const int* __restrict__ col, float* __restrict__ deg, int E) {
    int stride = gridDim.x * blockDim.x;
    for (int i = blockIdx.x * blockDim.x + threadIdx.x; i < E; i += stride)
        atomicAdd(&deg[col[i]], 1.0f);
}
__global__ void fb_dinv(float* __restrict__ d, int N) {
    int i = blockIdx.x * blockDim.x + threadIdx.x;
    if (i < N) d[i] = rsqrtf(d[i] + 1.0f);
}
__global__ void fb_h1p(const float* __restrict__ x, const float* __restrict__ W1, float* __restrict__ h1p, int N) {
    __shared__ float sW[144];
    if (threadIdx.x < 144) sW[threadIdx.x] = W1[threadIdx.x];
    __syncthreads();
    int i = blockIdx.x * blockDim.x + threadIdx.x;
    if (i >= N) return;
    float xi[9];
#pragma unroll
    for (int q = 0; q < 9; ++q) xi[q] = x[i * 9 + q];
#pragma unroll
    for (int ff = 0; ff < 16; ++ff) {
        float a = 0.f;
#pragma unroll
        for (int q = 0; q < 9; ++q) a = fmaf(xi[q], sW[q * 16 + ff], a);
        h1p[i * 16 + ff] = a;
    }
}
__global__ void fb_sc1(const int* __restrict__ row, const int* __restrict__ col, const float* __restrict__ dinv,
                       const float* __restrict__ h1p, float* __restrict__ agg1, long total) {
    long stride = (long)gridDim.x * blockDim.x;
    for (long t = (long)blockIdx.x * blockDim.x + threadIdx.x; t < total; t += stride) {
        int e = (int)(t >> 4), ff = (int)(t & 15);
        int r = row[e], c = col[e];
        atomicAdd(&agg1[c * 16 + ff], h1p[r * 16 + ff] * dinv[r] * dinv[c]);
    }
}
__global__ void fb_fin1(const float* __restrict__ agg1, const float* __restrict__ h1p, const float* __restrict__ dinv,
                        const float* __restrict__ b1, const float* __restrict__ W2, float* __restrict__ h2p, int N) {
    __shared__ float sW2[16], sb1[16];
    if (threadIdx.x < 16) { sW2[threadIdx.x] = W2[threadIdx.x]; sb1[threadIdx.x] = b1[threadIdx.x]; }
    __syncthreads();
    int i = blockIdx.x * blockDim.x + threadIdx.x;
    if (i >= N) return;
    float di = dinv[i], self = di * di, a = 0.f;
#pragma unroll
    for (int ff = 0; ff < 16; ++ff) {
        float v = agg1[i * 16 + ff] + h1p[i * 16 + ff] * self + sb1[ff];
        a = fmaf(fmaxf(v, 0.f), sW2[ff], a);
    }
    h2p[i] = a;
}
__global__ void fb_sc2(const int* __restrict__ row, const int* __restrict__ col, const float* __restrict__ dinv,
                       const float* __restrict__ h2p, float* __restrict__ out, int E) {
    int stride = gridDim.x * blockDim.x;
    for (int e = blockIdx.x * blockDim.x + threadIdx.x; e < E; e += stride) {
        int r = row[e], c = col[e];
        atomicAdd(&out[c], h2p[r] * dinv[r] * dinv[c]);
    }
}
__global__ void fb_fin2(float* __restrict__ out, const float* __restrict__ h2p, const float* __restrict__ dinv,
                        const float* __restrict__ b2, int N) {
    int i = blockIdx.x * blockDim.x + threadIdx.x;
    if (i < N) {
        float di = dinv[i];
        out[i] = fmaxf(out[i] + h2p[i] * di * di + b2[0], 0.f);
    }
}

// ============================ launcher ============================

extern "C" void kernel_launch(void* const* d_in, const int* in_sizes, int n_in,
                              void* d_out, int out_size, void* d_ws, size_t ws_size,
                              hipStream_t stream) {
    const float* x  = (const float*)d_in[0];
    const int*   ei = (const int*)d_in[1];
    const float* W1 = (const float*)d_in[2];
    const float* b1 = (const float*)d_in[3];
    const float* W2 = (const float*)d_in[4];
    const float* b2 = (const float*)d_in[5];
    float* out = (float*)d_out;
    const int* row = ei;
    const int* col = ei + NE;
    char* ws = (char*)d_ws;

    constexpr size_t OFF_EB = 0;                          // 25,600,000 B
    constexpr size_t OFF_X  = 25600000;                   // 6,600,000 B region (X = 6.4MB; g1a/g1b overlay at +32KB, valid after passB)
    constexpr size_t OFF_CT = OFF_X + 6600000;            // 4096 B
    constexpr size_t OFF_CB = OFF_CT + 4096;              // 4096 B
    constexpr size_t OFF_DI = OFF_CB + 4096;              // 400,000 B
    constexpr size_t OFF_H2 = OFF_DI + 400000;            // 400,000 B
    constexpr size_t OFF_GG = OFF_H2 + 400000;            // 400,000 B
    constexpr size_t WS_NEED = OFF_GG + 400000;           // ~33.4 MB

    if (ws_size >= WS_NEED) {
        int*   eb    = (int*)(ws + OFF_EB);
        int*   X     = (int*)(ws + OFF_X);
        int*   ctot  = (int*)(ws + OFF_CT);
        int*   cbase = (int*)(ws + OFF_CB);
        float* dinv  = (float*)(ws + OFF_DI);
        float* h2a   = (float*)(ws + OFF_H2);
        float* gg    = (float*)(ws + OFF_GG);
        // overlay: X's chunk-offset region (b>0) is dead after passB; bucket starts live at X[0..NBKT]
        float* g1a   = (float*)(ws + OFF_X + 32768);      // 3,200,000 B
        float* g1b   = (float*)(ws + OFF_X + 32768 + 3200000);  // 3,200,000 B (ends < 6.6MB region)

        histA<<<NB, 512, 0, stream>>>(col, X);
        scan1<<<NCH, 512, 0, stream>>>(X, ctot);
        scan2<<<1, 1024, 0, stream>>>(ctot, cbase);
        scan3<<<(TOTBINS + 255) / 256, 256, 0, stream>>>(X, cbase);
        passB<<<NB, 512, 0, stream>>>(row, col, X, eb);
        int gridK = (NBKT + 3) / 4;   // 1563
        passC<<<gridK, 256, 0, stream>>>(eb, X, x, W1, dinv, g1a, g1b);
        passE<0><<<gridK, 256, 0, stream>>>(eb, X, g1a, dinv, b1, W2, nullptr, h2a);
        passE<1><<<gridK, 256, 0, stream>>>(eb, X, g1b, dinv, b1, W2, h2a, gg);
        passF<<<gridK, 256, 0, stream>>>(eb, X, gg, dinv, b2, out);
    } else {
        // fallback: global-atomic version (needs ~13.8 MB)
        float* dinv = (float*)(ws);
        float* h1p  = (float*)(ws + 524288);
        float* agg1 = (float*)(ws + 6924288);
        float* h2p  = (float*)(ws + 13324288);
        hipMemsetAsync(dinv, 0, NN * sizeof(float), stream);
        hipMemsetAsync(agg1, 0, NN * 16 * sizeof(float), stream);
        hipMemsetAsync(out, 0, NN * sizeof(float), stream);
        const int B = 256;
        int gridN = (NN + B - 1) / B;
        fb_deg<<<4096, B, 0, stream>>>(col, dinv, NE);
        fb_dinv<<<gridN, B, 0, stream>>>(dinv, NN);
        fb_h1p<<<gridN, B, 0, stream>>>(x, W1, h1p, NN);
        fb_sc1<<<8192, B, 0, stream>>>(row, col, dinv, h1p, agg1, (long)NE * 16);
        fb_fin1<<<gridN, B, 0, stream>>>(agg1, h1p, dinv, b1, W2, h2p, NN);
        fb_sc2<<<4096, B, 0, stream>>>(row, col, dinv, h2p, out, NE);
        fb_fin2<<<gridN, B, 0, stream>>>(out, h2p, dinv, b2, NN);
    }
}